// Round 2
// baseline (166.882 us; speedup 1.0000x reference)
//
#include <hip/hip_runtime.h>
#include <hip/hip_bf16.h>

// Problem constants
#define NT      32      // time steps
#define FEAT    128     // in/out features per step
#define TRIB    8       // band width in blocks
#define BATCH   8192
#define INSIZE  (NT*FEAT)   // 4096
#define OUTCOLS (NT*FEAT)   // 4096

typedef __bf16 bf16;
typedef __bf16 bf16x4 __attribute__((ext_vector_type(4)));
typedef __bf16 bf16x8 __attribute__((ext_vector_type(8)));
typedef float  f32x4  __attribute__((ext_vector_type(4)));

__host__ __device__ __forceinline__ int nb_of(int i){ return i < TRIB ? i + 1 : TRIB; }
__host__ __device__ __forceinline__ int lo_of(int i){ int l = i - TRIB + 1; return l > 0 ? l : 0; }
// element offset of packed bf16 band for time step i: sum_{j<i} nb(j) * 128*128
__host__ __device__ __forceinline__ long off_of(int i){
  long sum = (i <= TRIB) ? (long)i*(i+1)/2 : (long)(TRIB*(TRIB+1)/2) + (long)(i - TRIB)*TRIB;
  return sum * (long)(FEAT*FEAT);
}

// ---------------- conversion kernels ----------------

__global__ void cvt_x_kernel(const float* __restrict__ x, bf16* __restrict__ xb, long n4){
  long idx = (long)blockIdx.x * blockDim.x + threadIdx.x;
  long stride = (long)gridDim.x * blockDim.x;
  const f32x4* src = (const f32x4*)x;
  bf16x4* dst = (bf16x4*)xb;
  for (long i = idx; i < n4; i += stride){
    f32x4 v = src[i];
    bf16x4 o;
    o.x = (bf16)v.x; o.y = (bf16)v.y; o.z = (bf16)v.z; o.w = (bf16)v.w;
    dst[i] = o;
  }
}

// one block per (time step i, row n): convert band row of W (<=1024 floats) to packed bf16
__global__ void cvt_w_kernel(const float* __restrict__ w, bf16* __restrict__ wp){
  int i = blockIdx.x;      // time step
  int n = blockIdx.y;      // row within output block
  int ktl = nb_of(i) * FEAT;   // band K length (<=1024)
  int lo  = lo_of(i) * FEAT;
  long src = (long)(i*FEAT + n) * INSIZE + lo;
  long dst = off_of(i) + (long)n * ktl;
  for (int e = threadIdx.x * 4; e < ktl; e += blockDim.x * 4){
    f32x4 v = *(const f32x4*)(w + src + e);
    bf16x4 o;
    o.x = (bf16)v.x; o.y = (bf16)v.y; o.z = (bf16)v.z; o.w = (bf16)v.w;
    *(bf16x4*)(wp + dst + e) = o;
  }
}

// ---------------- banded GEMM, 3-deep pipelined ----------------
// BM=256 (batch rows), BN=128 (one time step), BK=64.
// 512 threads = 8 waves in 4(M) x 2(N); each wave owns 64x64 = 4x4 frags 16x16.
// LDS: 3 stages x (A 256x64 + B 128x64) bf16 = 144 KiB.
// T2 swizzle: 16B slot s at row r stored at slot s^(r&7); achieved by
// inverse-permuting the GLOBAL source per lane (LDS dest stays linear for
// global_load_lds), and applying the same XOR on ds_read addresses.

#define BM 256
#define BN 128
#define BK 64
#define NSTAGE 3
#define TILE_ELEMS (BM*BK + BN*BK)   // bf16 elements per stage

__device__ __forceinline__ void gload16(const void* g, void* l){
  __builtin_amdgcn_global_load_lds(
      (__attribute__((address_space(1))) unsigned int*)(unsigned long long)g,
      (__attribute__((address_space(3))) unsigned int*)l,
      16, 0, 0);
}

__global__ __launch_bounds__(512)
void gemm_band_kernel(const bf16* __restrict__ xb, const bf16* __restrict__ wp,
                      const float* __restrict__ bias, float* __restrict__ out){
  __shared__ __align__(16) bf16 lds[NSTAGE * TILE_ELEMS];

  const int i  = blockIdx.x;          // time step 0..31
  const int mt = blockIdx.y;          // m-tile 0..31
  const int m0 = mt * BM;
  const int nbK = nb_of(i);           // 1..8
  const int ntiles = nbK * (FEAT/BK); // 2..16 K-tiles of BK=64
  const int lo = lo_of(i) * FEAT;
  const int Kt = nbK * FEAT;
  const long wpo = off_of(i);

  const int tid  = threadIdx.x;
  const int lane = tid & 63;
  const int wid  = tid >> 6;          // 0..7
  const int wr   = wid >> 1;          // 0..3 -> 64-row M strip
  const int wc   = wid & 1;           // 0..1 -> 64-col N strip

  // stage K-tile t into lds stage (t % NSTAGE). 6 global_load_lds per wave.
  auto stage = [&](int t){
    bf16* base  = lds + (t % NSTAGE) * TILE_ELEMS;
    bf16* Abase = base;
    bf16* Bbase = base + BM*BK;
    const int kbase = lo + t * BK;
    // A: 2048 16B-chunks; wave wid covers chunks [wid*256, wid*256+255]
    #pragma unroll
    for (int j = 0; j < 4; ++j){
      const int c = wid*256 + j*64 + lane;
      const int r = c >> 3;                    // A row 0..255
      const int s = (c & 7) ^ (r & 7);         // inverse swizzle on source
      gload16(xb + (long)(m0 + r) * INSIZE + kbase + s*8,
              (void*)(Abase + (wid*256 + j*64) * 8));
    }
    // B: 1024 16B-chunks; wave wid covers chunks [wid*128, wid*128+127]
    #pragma unroll
    for (int j = 0; j < 2; ++j){
      const int c = wid*128 + j*64 + lane;
      const int r = c >> 3;                    // B row 0..127
      const int s = (c & 7) ^ (r & 7);
      gload16(wp + wpo + (long)r * Kt + t*BK + s*8,
              (void*)(Bbase + (wid*128 + j*64) * 8));
    }
  };

  // prologue: fill pipeline 2 deep (ntiles >= 2 always)
  stage(0);
  stage(1);

  f32x4 acc[4][4] = {};

  for (int t = 0; t < ntiles; ++t){
    // tile t's 6 loads are the oldest outstanding; vmcnt retires in-order,
    // so vmcnt(6) leaves tile t+1's loads in flight (T4: never drain to 0).
    if (t + 1 < ntiles) asm volatile("s_waitcnt vmcnt(6)" ::: "memory");
    else                asm volatile("s_waitcnt vmcnt(0)" ::: "memory");
    __builtin_amdgcn_s_barrier();
    asm volatile("" ::: "memory");

    // prefetch t+2 into the stage all waves just finished reading (iter t-1)
    if (t + 2 < ntiles) stage(t + 2);

    const bf16* base = lds + (t % NSTAGE) * TILE_ELEMS;
    const bf16* Ab = base;
    const bf16* Bb = base + BM*BK;

    bf16x8 a[4][2], b[4][2];
    #pragma unroll
    for (int mi = 0; mi < 4; ++mi){
      const int row = wr*64 + mi*16 + (lane & 15);
      #pragma unroll
      for (int ks = 0; ks < 2; ++ks){
        const int slot = (ks*4 + (lane >> 4)) ^ (row & 7);   // T2 read swizzle
        a[mi][ks] = *(const bf16x8*)(Ab + row*BK + slot*8);
      }
    }
    #pragma unroll
    for (int ni = 0; ni < 4; ++ni){
      const int row = wc*64 + ni*16 + (lane & 15);
      #pragma unroll
      for (int ks = 0; ks < 2; ++ks){
        const int slot = (ks*4 + (lane >> 4)) ^ (row & 7);
        b[ni][ks] = *(const bf16x8*)(Bb + row*BK + slot*8);
      }
    }

    __builtin_amdgcn_s_setprio(1);
    #pragma unroll
    for (int ks = 0; ks < 2; ++ks)
      #pragma unroll
      for (int mi = 0; mi < 4; ++mi)
        #pragma unroll
        for (int ni = 0; ni < 4; ++ni)
          acc[mi][ni] = __builtin_amdgcn_mfma_f32_16x16x32_bf16(
              a[mi][ks], b[ni][ks], acc[mi][ni], 0, 0, 0);
    __builtin_amdgcn_s_setprio(0);
    asm volatile("" ::: "memory");
  }

  // epilogue: C/D layout col = lane&15, row = (lane>>4)*4 + reg
  const int cfrag = lane & 15;
  const int rgrp  = lane >> 4;
  #pragma unroll
  for (int ni = 0; ni < 4; ++ni){
    const int gcol = i*FEAT + wc*64 + ni*16 + cfrag;
    const float bval = bias[gcol];
    #pragma unroll
    for (int mi = 0; mi < 4; ++mi){
      #pragma unroll
      for (int r2 = 0; r2 < 4; ++r2){
        const int m = m0 + wr*64 + mi*16 + rgrp*4 + r2;
        out[(long)m * OUTCOLS + gcol] = acc[mi][ni][r2] + bval;
      }
    }
  }
}

// ---------------- fallback (tiny ws): naive fp32, band-limited ----------------
__global__ void naive_kernel(const float* __restrict__ x, const float* __restrict__ w,
                             const float* __restrict__ bias, float* __restrict__ out){
  long idx = (long)blockIdx.x * blockDim.x + threadIdx.x;  // over 8192*4096
  int o = (int)(idx & (OUTCOLS - 1));
  int b = (int)(idx >> 12);
  int i = o >> 7;
  int lo = lo_of(i) * FEAT, hi = (i + 1) * FEAT;
  const float* xr = x + (long)b * INSIZE;
  const float* wr = w + (long)o * INSIZE;
  float s = bias[o];
  for (int k = lo; k < hi; k += 4){
    f32x4 xv = *(const f32x4*)(xr + k);
    f32x4 wv = *(const f32x4*)(wr + k);
    s += xv.x*wv.x + xv.y*wv.y + xv.z*wv.z + xv.w*wv.w;
  }
  out[idx] = s;
}

// ---------------- launch ----------------
extern "C" void kernel_launch(void* const* d_in, const int* in_sizes, int n_in,
                              void* d_out, int out_size, void* d_ws, size_t ws_size,
                              hipStream_t stream) {
  const float* x    = (const float*)d_in[0];
  const float* w    = (const float*)d_in[1];
  const float* bias = (const float*)d_in[2];
  // d_in[3] = mask (block-banded, reproduced analytically) — unused
  float* out = (float*)d_out;

  const size_t x_bytes = (size_t)BATCH * INSIZE * sizeof(bf16);        // 64 MiB
  const size_t w_bytes = (size_t)228 * FEAT * FEAT * sizeof(bf16);     // ~7.5 MiB packed band
  if (ws_size >= x_bytes + w_bytes){
    bf16* xb = (bf16*)d_ws;
    bf16* wp = (bf16*)((char*)d_ws + x_bytes);
    cvt_x_kernel<<<2048, 256, 0, stream>>>(x, xb, (long)BATCH * INSIZE / 4);
    cvt_w_kernel<<<dim3(NT, FEAT), 256, 0, stream>>>(w, wp);
    gemm_band_kernel<<<dim3(NT, BATCH/BM), 512, 0, stream>>>(xb, wp, bias, out);
  } else {
    naive_kernel<<<(long)BATCH * OUTCOLS / 256, 256, 0, stream>>>(x, w, bias, out);
  }
}

// Round 3
// 138.518 us; speedup vs baseline: 1.2048x; 1.2048x over previous
//
#include <hip/hip_runtime.h>
#include <hip/hip_bf16.h>

// Problem constants
#define NT      32      // time steps
#define FEAT    128     // in/out features per step
#define TRIB    8       // band width in blocks
#define BATCH   8192
#define INSIZE  (NT*FEAT)   // 4096
#define OUTCOLS (NT*FEAT)   // 4096

typedef __bf16 bf16;
typedef __bf16 bf16x4 __attribute__((ext_vector_type(4)));
typedef __bf16 bf16x8 __attribute__((ext_vector_type(8)));
typedef float  f32x4  __attribute__((ext_vector_type(4)));

__host__ __device__ __forceinline__ int nb_of(int i){ return i < TRIB ? i + 1 : TRIB; }
__host__ __device__ __forceinline__ int lo_of(int i){ int l = i - TRIB + 1; return l > 0 ? l : 0; }
// element offset of packed bf16 band for time step i
__host__ __device__ __forceinline__ long off_of(int i){
  long sum = (i <= TRIB) ? (long)i*(i+1)/2 : (long)(TRIB*(TRIB+1)/2) + (long)(i - TRIB)*TRIB;
  return sum * (long)(FEAT*FEAT);
}

// ---------------- conversion kernels ----------------

__global__ void cvt_x_kernel(const float* __restrict__ x, bf16* __restrict__ xb, long n4){
  long idx = (long)blockIdx.x * blockDim.x + threadIdx.x;
  long stride = (long)gridDim.x * blockDim.x;
  const f32x4* src = (const f32x4*)x;
  bf16x4* dst = (bf16x4*)xb;
  for (long i = idx; i < n4; i += stride){
    f32x4 v = src[i];
    bf16x4 o;
    o.x = (bf16)v.x; o.y = (bf16)v.y; o.z = (bf16)v.z; o.w = (bf16)v.w;
    dst[i] = o;
  }
}

__global__ void cvt_w_kernel(const float* __restrict__ w, bf16* __restrict__ wp){
  int i = blockIdx.x;      // time step
  int n = blockIdx.y;      // row within output block
  int ktl = nb_of(i) * FEAT;
  int lo  = lo_of(i) * FEAT;
  long src = (long)(i*FEAT + n) * INSIZE + lo;
  long dst = off_of(i) + (long)n * ktl;
  for (int e = threadIdx.x * 4; e < ktl; e += blockDim.x * 4){
    f32x4 v = *(const f32x4*)(w + src + e);
    bf16x4 o;
    o.x = (bf16)v.x; o.y = (bf16)v.y; o.z = (bf16)v.z; o.w = (bf16)v.w;
    *(bf16x4*)(wp + dst + e) = o;
  }
}

// ---------------- banded GEMM, 2-phase-per-tile pipelined ----------------
// BM=512, BN=128 (one time step), BK=32. 512 threads = 8 waves (4M x 2N),
// wave tile 128x64 = 8x4 frags of 16x16. 3-stage LDS pipeline (120 KiB).
//
// LDS layout (superrow packed, conflict-free at 64B rows):
//   two consecutive 64B rows packed into one 128B superrow; 16B slot q of
//   superrow u holds (row = 2u + (s8>>2), kslot = s8&3) where s8 = q ^ (u&7).
//   Applied by pre-permuting the GLOBAL source (linear LDS dest for
//   global_load_lds) and using the same XOR on ds_read addresses.

#define BM 512
#define BN 128
#define BK 32
#define NSTAGE 3
#define A_ELEMS (BM*BK)              // 16384
#define B_ELEMS (BN*BK)              // 4096
#define TILE_ELEMS (A_ELEMS + B_ELEMS)

__device__ __forceinline__ void gload16(const void* g, void* l){
  __builtin_amdgcn_global_load_lds(
      (__attribute__((address_space(1))) unsigned int*)(unsigned long long)g,
      (__attribute__((address_space(3))) unsigned int*)l,
      16, 0, 0);
}

__global__ __launch_bounds__(512, 2)
void gemm_band_kernel(const bf16* __restrict__ xb, const bf16* __restrict__ wp,
                      const float* __restrict__ bias, float* __restrict__ out){
  __shared__ __align__(16) bf16 lds[NSTAGE * TILE_ELEMS];   // 120 KiB

  const int bid = blockIdx.x;
  const int mt  = bid & 15;            // fast dim: m-tile (L2 sliding window)
  const int i   = 31 - (bid >> 4);     // slow dim, descending (LPT: heavy first)
  const int m0  = mt * BM;
  const int nbK = nb_of(i);
  const int ntiles = nbK * (FEAT / BK);    // 4..32
  const int lo  = lo_of(i) * FEAT;
  const int Kt  = nbK * FEAT;
  const long wpo = off_of(i);

  const int tid  = threadIdx.x;
  const int lane = tid & 63;
  const int wid  = tid >> 6;           // 0..7
  const int wr   = wid >> 1;           // 0..3 -> 128-row M strip
  const int wc   = wid & 1;            // 0..1 -> 64-col N strip
  const int fr   = lane & 15;
  const int ks   = lane >> 4;          // 0..3 k-slot (8 bf16 each)

  // -------- loop-invariant LDS read offsets (elements, stage-relative) -----
  int offA[8], offB[4];
  #pragma unroll
  for (int mi = 0; mi < 8; ++mi){
    const int row = wr*128 + mi*16 + fr;
    const int u = row >> 1;
    const int q = (((row & 1) << 2) | ks) ^ (u & 7);
    offA[mi] = u*64 + q*8;
  }
  #pragma unroll
  for (int ni = 0; ni < 4; ++ni){
    const int row = wc*64 + ni*16 + fr;
    const int u = row >> 1;
    const int q = (((row & 1) << 2) | ks) ^ (u & 7);
    offB[ni] = u*64 + q*8;
  }

  // -------- loop-invariant gload source bases + LDS dest bases -------------
  // A: 2048 16B-chunks/stage; this thread owns chunks d = wid*256 + j*64 + lane
  const bf16* srcA[4];
  int dstA[4];
  #pragma unroll
  for (int j = 0; j < 4; ++j){
    const int d = wid*256 + j*64 + lane;
    const int u = d >> 3, qq = d & 7;
    const int s8 = qq ^ (u & 7);
    const int r  = 2*u + (s8 >> 2);
    const int sa = s8 & 3;
    srcA[j] = xb + (long)(m0 + r) * INSIZE + lo + sa*8;
    dstA[j] = (wid*256 + j*64) * 8;           // wave-uniform base (lane*16B added by HW)
  }
  const bf16* srcB;
  {
    const int d = wid*64 + lane;
    const int u = d >> 3, qq = d & 7;
    const int s8 = qq ^ (u & 7);
    const int r  = 2*u + (s8 >> 2);
    const int sb = s8 & 3;
    srcB = wp + wpo + (long)r * Kt + sb*8;
  }
  const int dstB = A_ELEMS + (wid*64) * 8;

  auto issueA = [&](int t, int j){
    bf16* base = lds + (t % NSTAGE) * TILE_ELEMS;
    gload16(srcA[j] + t*BK, base + dstA[j]);
  };
  auto issueB = [&](int t){
    bf16* base = lds + (t % NSTAGE) * TILE_ELEMS;
    gload16(srcB + t*BK, base + dstB);
  };

  // -------- prologue: fill 2 stages (ntiles >= 4 always) -------------------
  #pragma unroll
  for (int j = 0; j < 4; ++j) issueA(0, j);
  issueB(0);
  #pragma unroll
  for (int j = 0; j < 4; ++j) issueA(1, j);
  issueB(1);

  f32x4 acc[8][4] = {};

  asm volatile("s_waitcnt vmcnt(5)" ::: "memory");   // my stage-0 loads landed
  __builtin_amdgcn_s_barrier();                      // everyone's landed
  asm volatile("" ::: "memory");

  int st = 0;   // t % NSTAGE
  for (int t = 0; t < ntiles; ++t){
    const bf16* Ab = lds + st * TILE_ELEMS;
    const bf16* Bb = Ab + A_ELEMS;
    const bool pf = (t + 2 < ntiles);

    // ---- phase A: read lower-half A frags + all B frags; issue 3 prefetch
    bf16x8 a0 = *(const bf16x8*)(Ab + offA[0]);
    bf16x8 a1 = *(const bf16x8*)(Ab + offA[1]);
    bf16x8 a2 = *(const bf16x8*)(Ab + offA[2]);
    bf16x8 a3 = *(const bf16x8*)(Ab + offA[3]);
    bf16x8 b0 = *(const bf16x8*)(Bb + offB[0]);
    bf16x8 b1 = *(const bf16x8*)(Bb + offB[1]);
    bf16x8 b2 = *(const bf16x8*)(Bb + offB[2]);
    bf16x8 b3 = *(const bf16x8*)(Bb + offB[3]);
    if (pf){ issueA(t+2, 0); issueA(t+2, 1); issueA(t+2, 2); }
    __builtin_amdgcn_s_barrier();
    asm volatile("" ::: "memory");
    __builtin_amdgcn_s_setprio(1);
    acc[0][0] = __builtin_amdgcn_mfma_f32_16x16x32_bf16(a0, b0, acc[0][0], 0,0,0);
    acc[0][1] = __builtin_amdgcn_mfma_f32_16x16x32_bf16(a0, b1, acc[0][1], 0,0,0);
    acc[0][2] = __builtin_amdgcn_mfma_f32_16x16x32_bf16(a0, b2, acc[0][2], 0,0,0);
    acc[0][3] = __builtin_amdgcn_mfma_f32_16x16x32_bf16(a0, b3, acc[0][3], 0,0,0);
    acc[1][0] = __builtin_amdgcn_mfma_f32_16x16x32_bf16(a1, b0, acc[1][0], 0,0,0);
    acc[1][1] = __builtin_amdgcn_mfma_f32_16x16x32_bf16(a1, b1, acc[1][1], 0,0,0);
    acc[1][2] = __builtin_amdgcn_mfma_f32_16x16x32_bf16(a1, b2, acc[1][2], 0,0,0);
    acc[1][3] = __builtin_amdgcn_mfma_f32_16x16x32_bf16(a1, b3, acc[1][3], 0,0,0);
    acc[2][0] = __builtin_amdgcn_mfma_f32_16x16x32_bf16(a2, b0, acc[2][0], 0,0,0);
    acc[2][1] = __builtin_amdgcn_mfma_f32_16x16x32_bf16(a2, b1, acc[2][1], 0,0,0);
    acc[2][2] = __builtin_amdgcn_mfma_f32_16x16x32_bf16(a2, b2, acc[2][2], 0,0,0);
    acc[2][3] = __builtin_amdgcn_mfma_f32_16x16x32_bf16(a2, b3, acc[2][3], 0,0,0);
    acc[3][0] = __builtin_amdgcn_mfma_f32_16x16x32_bf16(a3, b0, acc[3][0], 0,0,0);
    acc[3][1] = __builtin_amdgcn_mfma_f32_16x16x32_bf16(a3, b1, acc[3][1], 0,0,0);
    acc[3][2] = __builtin_amdgcn_mfma_f32_16x16x32_bf16(a3, b2, acc[3][2], 0,0,0);
    acc[3][3] = __builtin_amdgcn_mfma_f32_16x16x32_bf16(a3, b3, acc[3][3], 0,0,0);
    __builtin_amdgcn_s_setprio(0);
    __builtin_amdgcn_s_barrier();
    asm volatile("" ::: "memory");

    // ---- phase B: read upper-half A frags; issue remaining 2 prefetch
    bf16x8 a4 = *(const bf16x8*)(Ab + offA[4]);
    bf16x8 a5 = *(const bf16x8*)(Ab + offA[5]);
    bf16x8 a6 = *(const bf16x8*)(Ab + offA[6]);
    bf16x8 a7 = *(const bf16x8*)(Ab + offA[7]);
    if (pf){ issueA(t+2, 3); issueB(t+2); }
    __builtin_amdgcn_s_barrier();
    asm volatile("" ::: "memory");
    __builtin_amdgcn_s_setprio(1);
    acc[4][0] = __builtin_amdgcn_mfma_f32_16x16x32_bf16(a4, b0, acc[4][0], 0,0,0);
    acc[4][1] = __builtin_amdgcn_mfma_f32_16x16x32_bf16(a4, b1, acc[4][1], 0,0,0);
    acc[4][2] = __builtin_amdgcn_mfma_f32_16x16x32_bf16(a4, b2, acc[4][2], 0,0,0);
    acc[4][3] = __builtin_amdgcn_mfma_f32_16x16x32_bf16(a4, b3, acc[4][3], 0,0,0);
    acc[5][0] = __builtin_amdgcn_mfma_f32_16x16x32_bf16(a5, b0, acc[5][0], 0,0,0);
    acc[5][1] = __builtin_amdgcn_mfma_f32_16x16x32_bf16(a5, b1, acc[5][1], 0,0,0);
    acc[5][2] = __builtin_amdgcn_mfma_f32_16x16x32_bf16(a5, b2, acc[5][2], 0,0,0);
    acc[5][3] = __builtin_amdgcn_mfma_f32_16x16x32_bf16(a5, b3, acc[5][3], 0,0,0);
    acc[6][0] = __builtin_amdgcn_mfma_f32_16x16x32_bf16(a6, b0, acc[6][0], 0,0,0);
    acc[6][1] = __builtin_amdgcn_mfma_f32_16x16x32_bf16(a6, b1, acc[6][1], 0,0,0);
    acc[6][2] = __builtin_amdgcn_mfma_f32_16x16x32_bf16(a6, b2, acc[6][2], 0,0,0);
    acc[6][3] = __builtin_amdgcn_mfma_f32_16x16x32_bf16(a6, b3, acc[6][3], 0,0,0);
    acc[7][0] = __builtin_amdgcn_mfma_f32_16x16x32_bf16(a7, b0, acc[7][0], 0,0,0);
    acc[7][1] = __builtin_amdgcn_mfma_f32_16x16x32_bf16(a7, b1, acc[7][1], 0,0,0);
    acc[7][2] = __builtin_amdgcn_mfma_f32_16x16x32_bf16(a7, b2, acc[7][2], 0,0,0);
    acc[7][3] = __builtin_amdgcn_mfma_f32_16x16x32_bf16(a7, b3, acc[7][3], 0,0,0);
    __builtin_amdgcn_s_setprio(0);
    // counted wait for NEXT tile's buffer, placed BEFORE the trailing barrier
    if (pf) asm volatile("s_waitcnt vmcnt(5)" ::: "memory");
    else    asm volatile("s_waitcnt vmcnt(0)" ::: "memory");
    __builtin_amdgcn_s_barrier();
    asm volatile("" ::: "memory");

    st = (st == NSTAGE-1) ? 0 : st + 1;
  }

  // -------- epilogue: C/D layout col = lane&15, row = (lane>>4)*4 + reg ----
  #pragma unroll
  for (int ni = 0; ni < 4; ++ni){
    const int gcol = i*FEAT + wc*64 + ni*16 + fr;
    const float bv = bias[gcol];
    #pragma unroll
    for (int mi = 0; mi < 8; ++mi){
      const int rbase = m0 + wr*128 + mi*16 + ks*4;
      #pragma unroll
      for (int r2 = 0; r2 < 4; ++r2)
        out[(long)(rbase + r2) * OUTCOLS + gcol] = acc[mi][ni][r2] + bv;
    }
  }
}

// ---------------- fallback (tiny ws): naive fp32, band-limited ----------------
__global__ void naive_kernel(const float* __restrict__ x, const float* __restrict__ w,
                             const float* __restrict__ bias, float* __restrict__ out){
  long idx = (long)blockIdx.x * blockDim.x + threadIdx.x;
  int o = (int)(idx & (OUTCOLS - 1));
  int b = (int)(idx >> 12);
  int i = o >> 7;
  int lo = lo_of(i) * FEAT, hi = (i + 1) * FEAT;
  const float* xr = x + (long)b * INSIZE;
  const float* wr = w + (long)o * INSIZE;
  float s = bias[o];
  for (int k = lo; k < hi; k += 4){
    f32x4 xv = *(const f32x4*)(xr + k);
    f32x4 wv = *(const f32x4*)(wr + k);
    s += xv.x*wv.x + xv.y*wv.y + xv.z*wv.z + xv.w*wv.w;
  }
  out[idx] = s;
}

// ---------------- launch ----------------
extern "C" void kernel_launch(void* const* d_in, const int* in_sizes, int n_in,
                              void* d_out, int out_size, void* d_ws, size_t ws_size,
                              hipStream_t stream) {
  const float* x    = (const float*)d_in[0];
  const float* w    = (const float*)d_in[1];
  const float* bias = (const float*)d_in[2];
  float* out = (float*)d_out;

  const size_t x_bytes = (size_t)BATCH * INSIZE * sizeof(bf16);        // 64 MiB
  const size_t w_bytes = (size_t)228 * FEAT * FEAT * sizeof(bf16);     // ~7.5 MiB
  if (ws_size >= x_bytes + w_bytes){
    bf16* xb = (bf16*)d_ws;
    bf16* wp = (bf16*)((char*)d_ws + x_bytes);
    cvt_x_kernel<<<2048, 256, 0, stream>>>(x, xb, (long)BATCH * INSIZE / 4);
    cvt_w_kernel<<<dim3(NT, FEAT), 256, 0, stream>>>(w, wp);
    gemm_band_kernel<<<dim3(NT * (BATCH/BM)), 512, 0, stream>>>(xb, wp, bias, out);
  } else {
    naive_kernel<<<(long)BATCH * OUTCOLS / 256, 256, 0, stream>>>(x, w, bias, out);
  }
}

// Round 4
// 138.161 us; speedup vs baseline: 1.2079x; 1.0026x over previous
//
#include <hip/hip_runtime.h>
#include <hip/hip_bf16.h>

// Problem constants
#define NT      32      // time steps
#define FEAT    128     // in/out features per step
#define TRIB    8       // band width in blocks
#define BATCH   8192
#define INSIZE  (NT*FEAT)   // 4096
#define OUTCOLS (NT*FEAT)   // 4096

typedef __bf16 bf16;
typedef __bf16 bf16x4 __attribute__((ext_vector_type(4)));
typedef __bf16 bf16x8 __attribute__((ext_vector_type(8)));
typedef float  f32x4  __attribute__((ext_vector_type(4)));

__host__ __device__ __forceinline__ int nb_of(int i){ return i < TRIB ? i + 1 : TRIB; }
__host__ __device__ __forceinline__ int lo_of(int i){ int l = i - TRIB + 1; return l > 0 ? l : 0; }
__host__ __device__ __forceinline__ long off_of(int i){
  long sum = (i <= TRIB) ? (long)i*(i+1)/2 : (long)(TRIB*(TRIB+1)/2) + (long)(i - TRIB)*TRIB;
  return sum * (long)(FEAT*FEAT);
}

// ---------------- conversion kernels ----------------

__global__ void cvt_x_kernel(const float* __restrict__ x, bf16* __restrict__ xb, long n4){
  long idx = (long)blockIdx.x * blockDim.x + threadIdx.x;
  long stride = (long)gridDim.x * blockDim.x;
  const f32x4* src = (const f32x4*)x;
  bf16x4* dst = (bf16x4*)xb;
  for (long i = idx; i < n4; i += stride){
    f32x4 v = src[i];
    bf16x4 o;
    o.x = (bf16)v.x; o.y = (bf16)v.y; o.z = (bf16)v.z; o.w = (bf16)v.w;
    dst[i] = o;
  }
}

__global__ void cvt_w_kernel(const float* __restrict__ w, bf16* __restrict__ wp){
  int i = blockIdx.x;
  int n = blockIdx.y;
  int ktl = nb_of(i) * FEAT;
  int lo  = lo_of(i) * FEAT;
  long src = (long)(i*FEAT + n) * INSIZE + lo;
  long dst = off_of(i) + (long)n * ktl;
  for (int e = threadIdx.x * 4; e < ktl; e += blockDim.x * 4){
    f32x4 v = *(const f32x4*)(w + src + e);
    bf16x4 o;
    o.x = (bf16)v.x; o.y = (bf16)v.y; o.z = (bf16)v.z; o.w = (bf16)v.w;
    *(bf16x4*)(wp + dst + e) = o;
  }
}

// ---------------- banded GEMM, pipelined, asm ds_read ----------------
// BM=512, BN=128, BK=32. 512 threads = 8 waves (4M x 2N), wave tile 128x64.
// 3-stage LDS (120 KiB). Superrow-packed XOR swizzle (conflict-free), applied
// via pre-permuted GLOBAL source (linear LDS dest for global_load_lds) and the
// same XOR on read addresses.
// KEY CHANGE vs R3: fragment loads are inline-asm ds_read_b128 so the
// compiler's LDS-DMA hazard pass cannot insert vmcnt(0) drains before them;
// data validity is guaranteed by our counted vmcnt + barrier schedule.
// Rule #18: barrier -> s_waitcnt lgkmcnt(0) -> sched_barrier(0) -> MFMA.

#define BM 512
#define BN 128
#define BK 32
#define NSTAGE 3
#define A_ELEMS (BM*BK)              // 16384
#define B_ELEMS (BN*BK)              // 4096
#define TILE_ELEMS (A_ELEMS + B_ELEMS)

__device__ __forceinline__ void gload16(const void* g, void* l){
  __builtin_amdgcn_global_load_lds(
      (__attribute__((address_space(1))) unsigned int*)(unsigned long long)g,
      (__attribute__((address_space(3))) unsigned int*)l,
      16, 0, 0);
}

__device__ __forceinline__ unsigned lds_addr(void* p){
  return (unsigned)(unsigned long long)(__attribute__((address_space(3))) void*)p;
}

__device__ __forceinline__ bf16x8 ds_read16(unsigned addr){
  bf16x8 r;
  asm volatile("ds_read_b128 %0, %1" : "=&v"(r) : "v"(addr));
  return r;
}

__global__ __launch_bounds__(512, 2)
void gemm_band_kernel(const bf16* __restrict__ xb, const bf16* __restrict__ wp,
                      const float* __restrict__ bias, float* __restrict__ out){
  __shared__ __align__(16) bf16 lds[NSTAGE * TILE_ELEMS];   // 120 KiB

  const int bid = blockIdx.x;
  const int mt  = bid & 15;            // fast dim: m-tile (L2/L3 sliding window)
  const int i   = 31 - (bid >> 4);     // slow dim, descending (LPT)
  const int m0  = mt * BM;
  const int nbK = nb_of(i);
  const int ntiles = nbK * (FEAT / BK);    // 4..32
  const int lo  = lo_of(i) * FEAT;
  const int Kt  = nbK * FEAT;
  const long wpo = off_of(i);

  const int tid  = threadIdx.x;
  const int lane = tid & 63;
  const int wid  = tid >> 6;           // 0..7
  const int wr   = wid >> 1;           // 0..3 -> 128-row M strip
  const int wc   = wid & 1;            // 0..1 -> 64-col N strip
  const int fr   = lane & 15;
  const int ks   = lane >> 4;          // 0..3 k-slot (8 bf16)

  const unsigned ldsBase = lds_addr((void*)lds);

  // -------- loop-invariant LDS read BYTE offsets (stage-relative) ----------
  unsigned offA[8], offB[4];
  #pragma unroll
  for (int mi = 0; mi < 8; ++mi){
    const int row = wr*128 + mi*16 + fr;
    const int u = row >> 1;
    const int q = (((row & 1) << 2) | ks) ^ (u & 7);
    offA[mi] = (unsigned)(u*64 + q*8) * 2u;
  }
  #pragma unroll
  for (int ni = 0; ni < 4; ++ni){
    const int row = wc*64 + ni*16 + fr;
    const int u = row >> 1;
    const int q = (((row & 1) << 2) | ks) ^ (u & 7);
    offB[ni] = (unsigned)(A_ELEMS*2) + (unsigned)(u*64 + q*8) * 2u;
  }

  // -------- loop-invariant gload source bases + LDS dest offsets -----------
  const bf16* srcA[4];
  int dstA[4];
  #pragma unroll
  for (int j = 0; j < 4; ++j){
    const int d = wid*256 + j*64 + lane;
    const int u = d >> 3, qq = d & 7;
    const int s8 = qq ^ (u & 7);
    const int r  = 2*u + (s8 >> 2);
    const int sa = s8 & 3;
    srcA[j] = xb + (long)(m0 + r) * INSIZE + lo + sa*8;
    dstA[j] = (wid*256 + j*64) * 8;
  }
  const bf16* srcB;
  {
    const int d = wid*64 + lane;
    const int u = d >> 3, qq = d & 7;
    const int s8 = qq ^ (u & 7);
    const int r  = 2*u + (s8 >> 2);
    const int sb = s8 & 3;
    srcB = wp + wpo + (long)r * Kt + sb*8;
  }
  const int dstB = A_ELEMS + (wid*64) * 8;

  auto issueA = [&](bf16* base, int t, int j){ gload16(srcA[j] + t*BK, base + dstA[j]); };
  auto issueB = [&](bf16* base, int t){ gload16(srcB + t*BK, base + dstB); };

  // -------- prologue: fill stages 0,1 --------------------------------------
  #pragma unroll
  for (int j = 0; j < 4; ++j) issueA(lds, 0, j);
  issueB(lds, 0);
  #pragma unroll
  for (int j = 0; j < 4; ++j) issueA(lds + TILE_ELEMS, 1, j);
  issueB(lds + TILE_ELEMS, 1);

  f32x4 acc[8][4] = {};

  asm volatile("s_waitcnt vmcnt(5)" ::: "memory");   // my stage-0 loads landed
  __builtin_amdgcn_s_barrier();                      // everyone's landed
  asm volatile("" ::: "memory");

  int stC = 0, stPf = 2;
  for (int t = 0; t < ntiles; ++t){
    const unsigned cA = ldsBase + (unsigned)stC * (TILE_ELEMS*2);
    bf16* pfBase = lds + stPf * TILE_ELEMS;
    const bool pf = (t + 2 < ntiles);

    // ---- phase A: issue 8 asm ds_reads; issue 3 prefetch gloads
    bf16x8 a0 = ds_read16(cA + offA[0]);
    bf16x8 a1 = ds_read16(cA + offA[1]);
    bf16x8 a2 = ds_read16(cA + offA[2]);
    bf16x8 a3 = ds_read16(cA + offA[3]);
    bf16x8 b0 = ds_read16(cA + offB[0]);
    bf16x8 b1 = ds_read16(cA + offB[1]);
    bf16x8 b2 = ds_read16(cA + offB[2]);
    bf16x8 b3 = ds_read16(cA + offB[3]);
    if (pf){ issueA(pfBase, t+2, 0); issueA(pfBase, t+2, 1); issueA(pfBase, t+2, 2); }
    __builtin_amdgcn_s_barrier();
    asm volatile("s_waitcnt lgkmcnt(0)" ::: "memory");
    __builtin_amdgcn_sched_barrier(0);
    __builtin_amdgcn_s_setprio(1);
    acc[0][0] = __builtin_amdgcn_mfma_f32_16x16x32_bf16(a0, b0, acc[0][0], 0,0,0);
    acc[0][1] = __builtin_amdgcn_mfma_f32_16x16x32_bf16(a0, b1, acc[0][1], 0,0,0);
    acc[0][2] = __builtin_amdgcn_mfma_f32_16x16x32_bf16(a0, b2, acc[0][2], 0,0,0);
    acc[0][3] = __builtin_amdgcn_mfma_f32_16x16x32_bf16(a0, b3, acc[0][3], 0,0,0);
    acc[1][0] = __builtin_amdgcn_mfma_f32_16x16x32_bf16(a1, b0, acc[1][0], 0,0,0);
    acc[1][1] = __builtin_amdgcn_mfma_f32_16x16x32_bf16(a1, b1, acc[1][1], 0,0,0);
    acc[1][2] = __builtin_amdgcn_mfma_f32_16x16x32_bf16(a1, b2, acc[1][2], 0,0,0);
    acc[1][3] = __builtin_amdgcn_mfma_f32_16x16x32_bf16(a1, b3, acc[1][3], 0,0,0);
    acc[2][0] = __builtin_amdgcn_mfma_f32_16x16x32_bf16(a2, b0, acc[2][0], 0,0,0);
    acc[2][1] = __builtin_amdgcn_mfma_f32_16x16x32_bf16(a2, b1, acc[2][1], 0,0,0);
    acc[2][2] = __builtin_amdgcn_mfma_f32_16x16x32_bf16(a2, b2, acc[2][2], 0,0,0);
    acc[2][3] = __builtin_amdgcn_mfma_f32_16x16x32_bf16(a2, b3, acc[2][3], 0,0,0);
    acc[3][0] = __builtin_amdgcn_mfma_f32_16x16x32_bf16(a3, b0, acc[3][0], 0,0,0);
    acc[3][1] = __builtin_amdgcn_mfma_f32_16x16x32_bf16(a3, b1, acc[3][1], 0,0,0);
    acc[3][2] = __builtin_amdgcn_mfma_f32_16x16x32_bf16(a3, b2, acc[3][2], 0,0,0);
    acc[3][3] = __builtin_amdgcn_mfma_f32_16x16x32_bf16(a3, b3, acc[3][3], 0,0,0);
    __builtin_amdgcn_s_setprio(0);
    __builtin_amdgcn_s_barrier();

    // ---- phase B: issue 4 asm ds_reads; issue remaining 2 prefetch gloads
    bf16x8 a4 = ds_read16(cA + offA[4]);
    bf16x8 a5 = ds_read16(cA + offA[5]);
    bf16x8 a6 = ds_read16(cA + offA[6]);
    bf16x8 a7 = ds_read16(cA + offA[7]);
    if (pf){ issueA(pfBase, t+2, 3); issueB(pfBase, t+2); }
    __builtin_amdgcn_s_barrier();
    asm volatile("s_waitcnt lgkmcnt(0)" ::: "memory");
    __builtin_amdgcn_sched_barrier(0);
    __builtin_amdgcn_s_setprio(1);
    acc[4][0] = __builtin_amdgcn_mfma_f32_16x16x32_bf16(a4, b0, acc[4][0], 0,0,0);
    acc[4][1] = __builtin_amdgcn_mfma_f32_16x16x32_bf16(a4, b1, acc[4][1], 0,0,0);
    acc[4][2] = __builtin_amdgcn_mfma_f32_16x16x32_bf16(a4, b2, acc[4][2], 0,0,0);
    acc[4][3] = __builtin_amdgcn_mfma_f32_16x16x32_bf16(a4, b3, acc[4][3], 0,0,0);
    acc[5][0] = __builtin_amdgcn_mfma_f32_16x16x32_bf16(a5, b0, acc[5][0], 0,0,0);
    acc[5][1] = __builtin_amdgcn_mfma_f32_16x16x32_bf16(a5, b1, acc[5][1], 0,0,0);
    acc[5][2] = __builtin_amdgcn_mfma_f32_16x16x32_bf16(a5, b2, acc[5][2], 0,0,0);
    acc[5][3] = __builtin_amdgcn_mfma_f32_16x16x32_bf16(a5, b3, acc[5][3], 0,0,0);
    acc[6][0] = __builtin_amdgcn_mfma_f32_16x16x32_bf16(a6, b0, acc[6][0], 0,0,0);
    acc[6][1] = __builtin_amdgcn_mfma_f32_16x16x32_bf16(a6, b1, acc[6][1], 0,0,0);
    acc[6][2] = __builtin_amdgcn_mfma_f32_16x16x32_bf16(a6, b2, acc[6][2], 0,0,0);
    acc[6][3] = __builtin_amdgcn_mfma_f32_16x16x32_bf16(a6, b3, acc[6][3], 0,0,0);
    acc[7][0] = __builtin_amdgcn_mfma_f32_16x16x32_bf16(a7, b0, acc[7][0], 0,0,0);
    acc[7][1] = __builtin_amdgcn_mfma_f32_16x16x32_bf16(a7, b1, acc[7][1], 0,0,0);
    acc[7][2] = __builtin_amdgcn_mfma_f32_16x16x32_bf16(a7, b2, acc[7][2], 0,0,0);
    acc[7][3] = __builtin_amdgcn_mfma_f32_16x16x32_bf16(a7, b3, acc[7][3], 0,0,0);
    __builtin_amdgcn_s_setprio(0);
    if (pf) asm volatile("s_waitcnt vmcnt(5)" ::: "memory");
    else    asm volatile("s_waitcnt vmcnt(0)" ::: "memory");
    __builtin_amdgcn_s_barrier();
    asm volatile("" ::: "memory");

    stC  = (stC  == NSTAGE-1) ? 0 : stC  + 1;
    stPf = (stPf == NSTAGE-1) ? 0 : stPf + 1;
  }

  // -------- epilogue: C/D layout col = lane&15, row = (lane>>4)*4 + reg ----
  #pragma unroll
  for (int ni = 0; ni < 4; ++ni){
    const int gcol = i*FEAT + wc*64 + ni*16 + fr;
    const float bv = bias[gcol];
    #pragma unroll
    for (int mi = 0; mi < 8; ++mi){
      const int rbase = m0 + wr*128 + mi*16 + ks*4;
      #pragma unroll
      for (int r2 = 0; r2 < 4; ++r2)
        out[(long)(rbase + r2) * OUTCOLS + gcol] = acc[mi][ni][r2] + bv;
    }
  }
}

// ---------------- fallback (tiny ws): naive fp32, band-limited ----------------
__global__ void naive_kernel(const float* __restrict__ x, const float* __restrict__ w,
                             const float* __restrict__ bias, float* __restrict__ out){
  long idx = (long)blockIdx.x * blockDim.x + threadIdx.x;
  int o = (int)(idx & (OUTCOLS - 1));
  int b = (int)(idx >> 12);
  int i = o >> 7;
  int lo = lo_of(i) * FEAT, hi = (i + 1) * FEAT;
  const float* xr = x + (long)b * INSIZE;
  const float* wr = w + (long)o * INSIZE;
  float s = bias[o];
  for (int k = lo; k < hi; k += 4){
    f32x4 xv = *(const f32x4*)(xr + k);
    f32x4 wv = *(const f32x4*)(wr + k);
    s += xv.x*wv.x + xv.y*wv.y + xv.z*wv.z + xv.w*wv.w;
  }
  out[idx] = s;
}

// ---------------- launch ----------------
extern "C" void kernel_launch(void* const* d_in, const int* in_sizes, int n_in,
                              void* d_out, int out_size, void* d_ws, size_t ws_size,
                              hipStream_t stream) {
  const float* x    = (const float*)d_in[0];
  const float* w    = (const float*)d_in[1];
  const float* bias = (const float*)d_in[2];
  float* out = (float*)d_out;

  const size_t x_bytes = (size_t)BATCH * INSIZE * sizeof(bf16);        // 64 MiB
  const size_t w_bytes = (size_t)228 * FEAT * FEAT * sizeof(bf16);     // ~7.5 MiB
  if (ws_size >= x_bytes + w_bytes){
    bf16* xb = (bf16*)d_ws;
    bf16* wp = (bf16*)((char*)d_ws + x_bytes);
    cvt_x_kernel<<<2048, 256, 0, stream>>>(x, xb, (long)BATCH * INSIZE / 4);
    cvt_w_kernel<<<dim3(NT, FEAT), 256, 0, stream>>>(w, wp);
    gemm_band_kernel<<<dim3(NT * (BATCH/BM)), 512, 0, stream>>>(xb, wp, bias, out);
  } else {
    naive_kernel<<<(long)BATCH * OUTCOLS / 256, 256, 0, stream>>>(x, w, bias, out);
  }
}

// Round 5
// 134.683 us; speedup vs baseline: 1.2391x; 1.0258x over previous
//
#include <hip/hip_runtime.h>
#include <hip/hip_bf16.h>

// Problem constants
#define NT      32      // time steps
#define FEAT    128     // in/out features per step
#define TRIB    8       // band width in blocks
#define BATCH   8192
#define INSIZE  (NT*FEAT)   // 4096
#define OUTCOLS (NT*FEAT)   // 4096

typedef __bf16 bf16;
typedef __bf16 bf16x4 __attribute__((ext_vector_type(4)));
typedef __bf16 bf16x8 __attribute__((ext_vector_type(8)));
typedef float  f32x4  __attribute__((ext_vector_type(4)));

__host__ __device__ __forceinline__ int nb_of(int i){ return i < TRIB ? i + 1 : TRIB; }
__host__ __device__ __forceinline__ int lo_of(int i){ int l = i - TRIB + 1; return l > 0 ? l : 0; }
__host__ __device__ __forceinline__ long off_of(int i){
  long sum = (i <= TRIB) ? (long)i*(i+1)/2 : (long)(TRIB*(TRIB+1)/2) + (long)(i - TRIB)*TRIB;
  return sum * (long)(FEAT*FEAT);
}

// ---------------- conversion kernels ----------------

__global__ void cvt_x_kernel(const float* __restrict__ x, bf16* __restrict__ xb, long n4){
  long idx = (long)blockIdx.x * blockDim.x + threadIdx.x;
  long stride = (long)gridDim.x * blockDim.x;
  const f32x4* src = (const f32x4*)x;
  bf16x4* dst = (bf16x4*)xb;
  for (long i = idx; i < n4; i += stride){
    f32x4 v = src[i];
    bf16x4 o;
    o.x = (bf16)v.x; o.y = (bf16)v.y; o.z = (bf16)v.z; o.w = (bf16)v.w;
    dst[i] = o;
  }
}

__global__ void cvt_w_kernel(const float* __restrict__ w, bf16* __restrict__ wp){
  int i = blockIdx.x;
  int n = blockIdx.y;
  int ktl = nb_of(i) * FEAT;
  int lo  = lo_of(i) * FEAT;
  long src = (long)(i*FEAT + n) * INSIZE + lo;
  long dst = off_of(i) + (long)n * ktl;
  for (int e = threadIdx.x * 4; e < ktl; e += blockDim.x * 4){
    f32x4 v = *(const f32x4*)(w + src + e);
    bf16x4 o;
    o.x = (bf16)v.x; o.y = (bf16)v.y; o.z = (bf16)v.z; o.w = (bf16)v.w;
    *(bf16x4*)(wp + dst + e) = o;
  }
}

// ---------------- banded GEMM, free-run 1-barrier pipeline ----------------
// BM=512, BN=128, BK=32. 512 threads = 8 waves (4M x 2N), wave tile 128x64.
// 3-stage LDS (120 KiB). Superrow-packed XOR swizzle (conflict-free), applied
// via pre-permuted GLOBAL source (linear LDS dest for global_load_lds) and the
// same XOR on read addresses.
//
// R5 KEY CHANGE: ONE barrier + ONE counted vmcnt per K-tile; no barrier
// between ds_read issue and MFMA (a wave's fragment reads are its own —
// lgkmcnt gates them; lgkm is in-order for DS ops so lgkmcnt(4) after 12
// issued reads means the first 8 landed). Waves free-run within a tile so
// LDS, MFMA, and VMEM pipes overlap across waves.
// Safety argument per tile t (NSTAGE=3):
//   - ds_reads(t) valid: prev-tile barrier came after every wave's vmcnt(5)
//     which retired stage(t)'s 5 loads.
//   - stage(t+2) overwrites buf(t-1): every wave completed its reads of
//     buf(t-1) (its lgkmcnt(0)) before the prev-tile barrier.
//   - this tile's trailing {lgkmcnt(0) done, vmcnt(5), barrier} re-establishes
//     both invariants for tile t+1.

#define BM 512
#define BN 128
#define BK 32
#define NSTAGE 3
#define A_ELEMS (BM*BK)              // 16384
#define B_ELEMS (BN*BK)              // 4096
#define TILE_ELEMS (A_ELEMS + B_ELEMS)

__device__ __forceinline__ void gload16(const void* g, void* l){
  __builtin_amdgcn_global_load_lds(
      (__attribute__((address_space(1))) unsigned int*)(unsigned long long)g,
      (__attribute__((address_space(3))) unsigned int*)l,
      16, 0, 0);
}

__device__ __forceinline__ unsigned lds_addr(void* p){
  return (unsigned)(unsigned long long)(__attribute__((address_space(3))) void*)p;
}

__device__ __forceinline__ bf16x8 ds_read16(unsigned addr){
  bf16x8 r;
  asm volatile("ds_read_b128 %0, %1" : "=&v"(r) : "v"(addr));
  return r;
}

__global__ __launch_bounds__(512, 2)
void gemm_band_kernel(const bf16* __restrict__ xb, const bf16* __restrict__ wp,
                      const float* __restrict__ bias, float* __restrict__ out){
  __shared__ __align__(16) bf16 lds[NSTAGE * TILE_ELEMS];   // 120 KiB

  const int bid = blockIdx.x;
  const int mt  = bid & 15;            // fast dim: m-tile (L2/L3 locality)
  const int i   = 31 - (bid >> 4);     // slow dim, descending (LPT)
  const int m0  = mt * BM;
  const int nbK = nb_of(i);
  const int ntiles = nbK * (FEAT / BK);    // 4..32
  const int lo  = lo_of(i) * FEAT;
  const int Kt  = nbK * FEAT;
  const long wpo = off_of(i);

  const int tid  = threadIdx.x;
  const int lane = tid & 63;
  const int wid  = tid >> 6;           // 0..7
  const int wr   = wid >> 1;           // 0..3 -> 128-row M strip
  const int wc   = wid & 1;            // 0..1 -> 64-col N strip
  const int fr   = lane & 15;
  const int ks   = lane >> 4;          // 0..3 k-slot (8 bf16)

  const unsigned ldsBase = lds_addr((void*)lds);

  // -------- loop-invariant LDS read BYTE offsets (stage-relative) ----------
  unsigned offA[8], offB[4];
  #pragma unroll
  for (int mi = 0; mi < 8; ++mi){
    const int row = wr*128 + mi*16 + fr;
    const int u = row >> 1;
    const int q = (((row & 1) << 2) | ks) ^ (u & 7);
    offA[mi] = (unsigned)(u*64 + q*8) * 2u;
  }
  #pragma unroll
  for (int ni = 0; ni < 4; ++ni){
    const int row = wc*64 + ni*16 + fr;
    const int u = row >> 1;
    const int q = (((row & 1) << 2) | ks) ^ (u & 7);
    offB[ni] = (unsigned)(A_ELEMS*2) + (unsigned)(u*64 + q*8) * 2u;
  }

  // -------- loop-invariant gload source bases + LDS dest offsets -----------
  const bf16* srcA[4];
  int dstA[4];
  #pragma unroll
  for (int j = 0; j < 4; ++j){
    const int d = wid*256 + j*64 + lane;
    const int u = d >> 3, qq = d & 7;
    const int s8 = qq ^ (u & 7);
    const int r  = 2*u + (s8 >> 2);
    const int sa = s8 & 3;
    srcA[j] = xb + (long)(m0 + r) * INSIZE + lo + sa*8;
    dstA[j] = (wid*256 + j*64) * 8;
  }
  const bf16* srcB;
  {
    const int d = wid*64 + lane;
    const int u = d >> 3, qq = d & 7;
    const int s8 = qq ^ (u & 7);
    const int r  = 2*u + (s8 >> 2);
    const int sb = s8 & 3;
    srcB = wp + wpo + (long)r * Kt + sb*8;
  }
  const int dstB = A_ELEMS + (wid*64) * 8;

  auto issueA = [&](bf16* base, int t, int j){ gload16(srcA[j] + t*BK, base + dstA[j]); };
  auto issueB = [&](bf16* base, int t){ gload16(srcB + t*BK, base + dstB); };

  // -------- prologue: fill stages 0,1 --------------------------------------
  #pragma unroll
  for (int j = 0; j < 4; ++j) issueA(lds, 0, j);
  issueB(lds, 0);
  #pragma unroll
  for (int j = 0; j < 4; ++j) issueA(lds + TILE_ELEMS, 1, j);
  issueB(lds + TILE_ELEMS, 1);

  f32x4 acc[8][4] = {};

  asm volatile("s_waitcnt vmcnt(5)" ::: "memory");   // my stage-0 loads landed
  __builtin_amdgcn_s_barrier();                      // everyone's landed
  asm volatile("" ::: "memory");

  int stC = 0, stPf = 2;
  for (int t = 0; t < ntiles; ++t){
    const unsigned cA = ldsBase + (unsigned)stC * (TILE_ELEMS*2);
    bf16* pfBase = lds + stPf * TILE_ELEMS;
    const bool pf = (t + 2 < ntiles);

    // ---- issue all 12 ds_reads (order: a0-3, b0-3, a4-7 — lgkm is in-order)
    bf16x8 a0 = ds_read16(cA + offA[0]);
    bf16x8 a1 = ds_read16(cA + offA[1]);
    bf16x8 a2 = ds_read16(cA + offA[2]);
    bf16x8 a3 = ds_read16(cA + offA[3]);
    bf16x8 b0 = ds_read16(cA + offB[0]);
    bf16x8 b1 = ds_read16(cA + offB[1]);
    bf16x8 b2 = ds_read16(cA + offB[2]);
    bf16x8 b3 = ds_read16(cA + offB[3]);
    bf16x8 a4 = ds_read16(cA + offA[4]);
    bf16x8 a5 = ds_read16(cA + offA[5]);
    bf16x8 a6 = ds_read16(cA + offA[6]);
    bf16x8 a7 = ds_read16(cA + offA[7]);

    // ---- issue next-next tile's staging immediately (HBM latency hides
    //      under this whole tile); writes buf(t-1), safe per prev barrier.
    if (pf){
      issueA(pfBase, t+2, 0); issueA(pfBase, t+2, 1);
      issueA(pfBase, t+2, 2); issueA(pfBase, t+2, 3);
      issueB(pfBase, t+2);
    }

    // ---- first 8 reads done -> first MFMA cluster
    asm volatile("s_waitcnt lgkmcnt(4)" ::: "memory");
    __builtin_amdgcn_sched_barrier(0);
    __builtin_amdgcn_s_setprio(1);
    acc[0][0] = __builtin_amdgcn_mfma_f32_16x16x32_bf16(a0, b0, acc[0][0], 0,0,0);
    acc[0][1] = __builtin_amdgcn_mfma_f32_16x16x32_bf16(a0, b1, acc[0][1], 0,0,0);
    acc[0][2] = __builtin_amdgcn_mfma_f32_16x16x32_bf16(a0, b2, acc[0][2], 0,0,0);
    acc[0][3] = __builtin_amdgcn_mfma_f32_16x16x32_bf16(a0, b3, acc[0][3], 0,0,0);
    acc[1][0] = __builtin_amdgcn_mfma_f32_16x16x32_bf16(a1, b0, acc[1][0], 0,0,0);
    acc[1][1] = __builtin_amdgcn_mfma_f32_16x16x32_bf16(a1, b1, acc[1][1], 0,0,0);
    acc[1][2] = __builtin_amdgcn_mfma_f32_16x16x32_bf16(a1, b2, acc[1][2], 0,0,0);
    acc[1][3] = __builtin_amdgcn_mfma_f32_16x16x32_bf16(a1, b3, acc[1][3], 0,0,0);
    acc[2][0] = __builtin_amdgcn_mfma_f32_16x16x32_bf16(a2, b0, acc[2][0], 0,0,0);
    acc[2][1] = __builtin_amdgcn_mfma_f32_16x16x32_bf16(a2, b1, acc[2][1], 0,0,0);
    acc[2][2] = __builtin_amdgcn_mfma_f32_16x16x32_bf16(a2, b2, acc[2][2], 0,0,0);
    acc[2][3] = __builtin_amdgcn_mfma_f32_16x16x32_bf16(a2, b3, acc[2][3], 0,0,0);
    acc[3][0] = __builtin_amdgcn_mfma_f32_16x16x32_bf16(a3, b0, acc[3][0], 0,0,0);
    acc[3][1] = __builtin_amdgcn_mfma_f32_16x16x32_bf16(a3, b1, acc[3][1], 0,0,0);
    acc[3][2] = __builtin_amdgcn_mfma_f32_16x16x32_bf16(a3, b2, acc[3][2], 0,0,0);
    acc[3][3] = __builtin_amdgcn_mfma_f32_16x16x32_bf16(a3, b3, acc[3][3], 0,0,0);
    __builtin_amdgcn_s_setprio(0);

    // ---- remaining 4 reads done -> second MFMA cluster
    asm volatile("s_waitcnt lgkmcnt(0)" ::: "memory");
    __builtin_amdgcn_sched_barrier(0);
    __builtin_amdgcn_s_setprio(1);
    acc[4][0] = __builtin_amdgcn_mfma_f32_16x16x32_bf16(a4, b0, acc[4][0], 0,0,0);
    acc[4][1] = __builtin_amdgcn_mfma_f32_16x16x32_bf16(a4, b1, acc[4][1], 0,0,0);
    acc[4][2] = __builtin_amdgcn_mfma_f32_16x16x32_bf16(a4, b2, acc[4][2], 0,0,0);
    acc[4][3] = __builtin_amdgcn_mfma_f32_16x16x32_bf16(a4, b3, acc[4][3], 0,0,0);
    acc[5][0] = __builtin_amdgcn_mfma_f32_16x16x32_bf16(a5, b0, acc[5][0], 0,0,0);
    acc[5][1] = __builtin_amdgcn_mfma_f32_16x16x32_bf16(a5, b1, acc[5][1], 0,0,0);
    acc[5][2] = __builtin_amdgcn_mfma_f32_16x16x32_bf16(a5, b2, acc[5][2], 0,0,0);
    acc[5][3] = __builtin_amdgcn_mfma_f32_16x16x32_bf16(a5, b3, acc[5][3], 0,0,0);
    acc[6][0] = __builtin_amdgcn_mfma_f32_16x16x32_bf16(a6, b0, acc[6][0], 0,0,0);
    acc[6][1] = __builtin_amdgcn_mfma_f32_16x16x32_bf16(a6, b1, acc[6][1], 0,0,0);
    acc[6][2] = __builtin_amdgcn_mfma_f32_16x16x32_bf16(a6, b2, acc[6][2], 0,0,0);
    acc[6][3] = __builtin_amdgcn_mfma_f32_16x16x32_bf16(a6, b3, acc[6][3], 0,0,0);
    acc[7][0] = __builtin_amdgcn_mfma_f32_16x16x32_bf16(a7, b0, acc[7][0], 0,0,0);
    acc[7][1] = __builtin_amdgcn_mfma_f32_16x16x32_bf16(a7, b1, acc[7][1], 0,0,0);
    acc[7][2] = __builtin_amdgcn_mfma_f32_16x16x32_bf16(a7, b2, acc[7][2], 0,0,0);
    acc[7][3] = __builtin_amdgcn_mfma_f32_16x16x32_bf16(a7, b3, acc[7][3], 0,0,0);
    __builtin_amdgcn_s_setprio(0);

    // ---- single per-tile sync: my stage(t+1) retired + everyone ready
    if (t + 1 < ntiles){
      if (pf) asm volatile("s_waitcnt vmcnt(5)" ::: "memory");
      else    asm volatile("s_waitcnt vmcnt(0)" ::: "memory");
      __builtin_amdgcn_s_barrier();
      asm volatile("" ::: "memory");
    }

    stC  = (stC  == NSTAGE-1) ? 0 : stC  + 1;
    stPf = (stPf == NSTAGE-1) ? 0 : stPf + 1;
  }

  // -------- epilogue: C/D layout col = lane&15, row = (lane>>4)*4 + reg ----
  #pragma unroll
  for (int ni = 0; ni < 4; ++ni){
    const int gcol = i*FEAT + wc*64 + ni*16 + fr;
    const float bv = bias[gcol];
    #pragma unroll
    for (int mi = 0; mi < 8; ++mi){
      const int rbase = m0 + wr*128 + mi*16 + ks*4;
      #pragma unroll
      for (int r2 = 0; r2 < 4; ++r2)
        out[(long)(rbase + r2) * OUTCOLS + gcol] = acc[mi][ni][r2] + bv;
    }
  }
}

// ---------------- fallback (tiny ws): naive fp32, band-limited ----------------
__global__ void naive_kernel(const float* __restrict__ x, const float* __restrict__ w,
                             const float* __restrict__ bias, float* __restrict__ out){
  long idx = (long)blockIdx.x * blockDim.x + threadIdx.x;
  int o = (int)(idx & (OUTCOLS - 1));
  int b = (int)(idx >> 12);
  int i = o >> 7;
  int lo = lo_of(i) * FEAT, hi = (i + 1) * FEAT;
  const float* xr = x + (long)b * INSIZE;
  const float* wr = w + (long)o * INSIZE;
  float s = bias[o];
  for (int k = lo; k < hi; k += 4){
    f32x4 xv = *(const f32x4*)(xr + k);
    f32x4 wv = *(const f32x4*)(wr + k);
    s += xv.x*wv.x + xv.y*wv.y + xv.z*wv.z + xv.w*wv.w;
  }
  out[idx] = s;
}

// ---------------- launch ----------------
extern "C" void kernel_launch(void* const* d_in, const int* in_sizes, int n_in,
                              void* d_out, int out_size, void* d_ws, size_t ws_size,
                              hipStream_t stream) {
  const float* x    = (const float*)d_in[0];
  const float* w    = (const float*)d_in[1];
  const float* bias = (const float*)d_in[2];
  float* out = (float*)d_out;

  const size_t x_bytes = (size_t)BATCH * INSIZE * sizeof(bf16);        // 64 MiB
  const size_t w_bytes = (size_t)228 * FEAT * FEAT * sizeof(bf16);     // ~7.5 MiB
  if (ws_size >= x_bytes + w_bytes){
    bf16* xb = (bf16*)d_ws;
    bf16* wp = (bf16*)((char*)d_ws + x_bytes);
    cvt_x_kernel<<<2048, 256, 0, stream>>>(x, xb, (long)BATCH * INSIZE / 4);
    cvt_w_kernel<<<dim3(NT, FEAT), 256, 0, stream>>>(w, wp);
    gemm_band_kernel<<<dim3(NT * (BATCH/BM)), 512, 0, stream>>>(xb, wp, bias, out);
  } else {
    naive_kernel<<<(long)BATCH * OUTCOLS / 256, 256, 0, stream>>>(x, w, bias, out);
  }
}